// Round 8
// baseline (3396.181 us; speedup 1.0000x reference)
//
#include <hip/hip_runtime.h>
#include <math.h>

#define E 8
#define S 6000
#define D 128
#define A 16
#define L 64
#define H 256
#define C 64
#define B 50
#define T 120
#define NSUB 2
#define FLAT 208      // L + A + D
#define RTOT 400      // E * B
#define RPB 10
#define NBLK (RTOT / RPB)   // 40, 5 blocks per e
#define BGRP 10
#define NBG 5

#define DT 0.5f
#define SQDT 0.70710678118654752440f

#define GNT 4096
#define GYMIN (-128.0f)
#define GDY 0.0625f
#define GINVDY 16.0f

typedef __attribute__((ext_vector_type(8))) short bf16x8;
typedef __attribute__((ext_vector_type(4))) float f32x4;

#define MFMA16(a, b, c) __builtin_amdgcn_mfma_f32_16x16x32_bf16(a, b, c, 0, 0, 0)

__device__ __forceinline__ float sigf(float x) {
    return __builtin_amdgcn_rcpf(1.0f + __expf(-x));
}

__device__ __forceinline__ unsigned short f2bf(float x) {
    union { float f; unsigned u; } v; v.f = x;
    return (unsigned short)((v.u + 0x8000u) >> 16);
}

// barrier that waits only LDS (lgkm); global loads stay in flight.
// "memory" clobber orders compiler-generated LDS ops across it.
__device__ __forceinline__ void bar_lgkm() {
    asm volatile("s_waitcnt lgkmcnt(0)" ::: "memory");
    __builtin_amdgcn_s_barrier();
}

// ---------------------------------------------------------------- g table
__global__ void gtab_kernel(const float* __restrict__ gw1, const float* __restrict__ gb1,
                            const float* __restrict__ gw2, const float* __restrict__ gb2,
                            float* __restrict__ tab) {
    int idx = blockIdx.x * blockDim.x + threadIdx.x;
    if (idx >= L * GNT) return;
    int l = idx / GNT, i = idx % GNT;
    float y = GYMIN + (float)i * GDY;
    const float* w1 = gw1 + l * H;
    const float* b1 = gb1 + l * H;
    const float* w2 = gw2 + l * H;
    float acc = gb2[l];
    #pragma unroll 4
    for (int h = 0; h < H; ++h) acc += w2[h] * (1.0f / (1.0f + __expf(-(y * w1[h] + b1[h]))));
    tab[idx] = acc;
}

// ---------------------------------------------------------------- B-fragment pack (bf16)
__global__ void packB_kernel(const float* __restrict__ src, unsigned short* __restrict__ dst,
                             int K, int N) {
    int idx = blockIdx.x * 256 + threadIdx.x;
    if (idx >= K * N) return;
    int j = idx & 7;
    int lane = (idx >> 3) & 63;
    int t2 = idx >> 9;               // n*(K/32) + kc
    int KC = K >> 5;
    int kc = t2 % KC, n = t2 / KC;
    int k = (kc << 5) + ((lane >> 4) << 3) + j;
    int c = (n << 4) + (lane & 15);
    union { float f; unsigned u; } v; v.f = src[k * N + c];
    dst[idx] = (unsigned short)((v.u + 0x7FFFu + ((v.u >> 16) & 1u)) >> 16);
}

// act_w z-rows per e -> bf16 fragments
__global__ void packAW_kernel(const float* __restrict__ aw, unsigned short* __restrict__ dst) {
    int idx = blockIdx.x * 256 + threadIdx.x;
    if (idx >= E * L * L) return;
    int e = idx >> 12;
    int rem = idx & 4095;
    int j = rem & 7;
    int lane = (rem >> 3) & 63;
    int t2 = rem >> 9;               // n*2 + kc
    int kc = t2 & 1, n = t2 >> 1;
    int k = (kc << 5) + ((lane >> 4) << 3) + j;
    int c = (n << 4) + (lane & 15);
    union { float f; unsigned u; } v; v.f = aw[((size_t)e * FLAT + k) * L + c];
    dst[idx] = (unsigned short)((v.u + 0x7FFFu + ((v.u >> 16) & 1u)) >> 16);
}

// ---------------------------------------------------------------- encoder + KL (+ z0 at t=0)
__global__ __launch_bounds__(256) void enc_kernel(const float* __restrict__ xs, const float* __restrict__ z0n,
                           const float* __restrict__ ew1, const float* __restrict__ eb1,
                           const float* __restrict__ ew2, const float* __restrict__ eb2,
                           const float* __restrict__ qw,  const float* __restrict__ qb,
                           const float* __restrict__ pm,  const float* __restrict__ pl,
                           float* __restrict__ z0buf, float* __restrict__ logqp0p) {
    int bid = blockIdx.x;            // (t*E + e)*NBG + bg
    int bg = bid % NBG; int te = bid / NBG; int e = te % E; int t = te / E;
    int tid = threadIdx.x;           // 256
    __shared__ float xsh[BGRP][D];
    __shared__ float c1s[BGRP][H];
    __shared__ float part[4][C][BGRP];
    __shared__ float ctxs[BGRP][C];
    __shared__ float qs[BGRP][2 * L];

    for (int i = tid; i < BGRP * D; i += 256) {
        int j = i / D, d = i % D;
        xsh[j][d] = xs[((size_t)e * S + (size_t)t * B + bg * BGRP + j) * D + d];
    }
    __syncthreads();
    {
        float bias = eb1[e * H + tid];
        float acc[BGRP];
        #pragma unroll
        for (int j = 0; j < BGRP; ++j) acc[j] = bias;
        const float* w = ew1 + (size_t)e * D * H + tid;
        #pragma unroll 4
        for (int d = 0; d < D; ++d) {
            float wv = w[(size_t)d * H];
            #pragma unroll
            for (int j = 0; j < BGRP; ++j) acc[j] += xsh[j][d] * wv;
        }
        #pragma unroll
        for (int j = 0; j < BGRP; ++j) c1s[j][tid] = sigf(acc[j]);
    }
    __syncthreads();
    {
        int c = tid & 63, kq = tid >> 6;
        float acc[BGRP];
        #pragma unroll
        for (int j = 0; j < BGRP; ++j) acc[j] = 0.f;
        const float* w = ew2 + (size_t)e * H * C + c;
        #pragma unroll 4
        for (int h = kq * 64; h < kq * 64 + 64; ++h) {
            float wv = w[(size_t)h * C];
            #pragma unroll
            for (int j = 0; j < BGRP; ++j) acc[j] += c1s[j][h] * wv;
        }
        #pragma unroll
        for (int j = 0; j < BGRP; ++j) part[kq][c][j] = acc[j];
    }
    __syncthreads();
    if (tid < C) {
        float bias = eb2[e * C + tid];
        #pragma unroll
        for (int j = 0; j < BGRP; ++j)
            ctxs[j][tid] = part[0][tid][j] + part[1][tid][j] + part[2][tid][j] + part[3][tid][j] + bias;
    }
    __syncthreads();
    if (tid < 2 * L) {
        float bias = qb[e * 2 * L + tid];
        float acc[BGRP];
        #pragma unroll
        for (int j = 0; j < BGRP; ++j) acc[j] = bias;
        const float* w = qw + (size_t)e * C * 2 * L + tid;
        #pragma unroll 4
        for (int c = 0; c < C; ++c) {
            float wv = w[(size_t)c * 2 * L];
            #pragma unroll
            for (int j = 0; j < BGRP; ++j) acc[j] += ctxs[j][c] * wv;
        }
        #pragma unroll
        for (int j = 0; j < BGRP; ++j) qs[j][tid] = acc[j];
    }
    __syncthreads();
    if (tid < L) {
        int l = tid;
        float kacc = 0.f;
        float m = pm[e * L + l], ls = pl[e * L + l];
        float inv2e = 1.0f / (2.0f * __expf(2.0f * ls));
        #pragma unroll
        for (int j = 0; j < BGRP; ++j) {
            float qm = qs[j][l], ql = qs[j][L + l];
            if (t == 0) {
                int b = bg * BGRP + j;
                float n = z0n[((size_t)e * B + b) * L + l];
                z0buf[((size_t)e * B + b) * L + l] = qm + __expf(ql) * n;
            }
            float dq = qm - m;
            kacc += ls - ql + (__expf(2.f * ql) + dq * dq) * inv2e - 0.5f;
        }
        #pragma unroll
        for (int off = 32; off; off >>= 1) kacc += __shfl_xor(kacc, off);
        if (l == 0) logqp0p[bid] = kacc / (float)B;
    }
}

// ---------------------------------------------------------------- action/x part of z_enc
__global__ __launch_bounds__(64) void ax_kernel(const float* __restrict__ xs, const float* __restrict__ actions,
                          const float* __restrict__ aw, const float* __restrict__ ab,
                          float* __restrict__ ax) {
    int bid = blockIdx.x;            // (t*E + e)*NBG + bg
    int bg = bid % NBG; int te = bid / NBG; int e = te % E; int t = te / E;
    int tid = threadIdx.x;           // 64
    __shared__ float xrow[BGRP][D];
    __shared__ float arow[BGRP][A];
    for (int i = tid; i < BGRP * D; i += 64) {
        int j = i / D, d = i % D;
        xrow[j][d] = xs[((size_t)e * S + (size_t)t * B + bg * BGRP + j) * D + d];
    }
    for (int i = tid; i < BGRP * A; i += 64) {
        int j = i / A, a = i % A;
        arow[j][a] = actions[((size_t)e * S + (size_t)t * B + bg * BGRP + j) * A + a];
    }
    __syncthreads();
    int l = tid;
    float acc[BGRP];
    float bias = ab[e * L + l];
    #pragma unroll
    for (int j = 0; j < BGRP; ++j) acc[j] = bias;
    const float* awp = aw + ((size_t)e * FLAT + L) * L + l;
    #pragma unroll 4
    for (int a = 0; a < A; ++a) {
        float wv = awp[(size_t)a * L];
        #pragma unroll
        for (int j = 0; j < BGRP; ++j) acc[j] += arow[j][a] * wv;
    }
    const float* xwp = aw + ((size_t)e * FLAT + L + A) * L + l;
    #pragma unroll 4
    for (int d = 0; d < D; ++d) {
        float wv = xwp[(size_t)d * L];
        #pragma unroll
        for (int j = 0; j < BGRP; ++j) acc[j] += xrow[j][d] * wv;
    }
    size_t rbase = (size_t)t * RTOT + e * B + bg * BGRP;
    #pragma unroll
    for (int j = 0; j < BGRP; ++j) ax[(rbase + j) * L + l] = acc[j];
}

// ---------------------------------------------------------------- sequential SDE loop
// 13 phases/step; raw lgkm-only barriers; all weights register-resident
// (W1 4 frags, W2 16 frags, W3 4 frags, W0 2 frags); no VGPR cap.
__global__ __launch_bounds__(1024, 1) void seq_kernel(
    const unsigned short* __restrict__ pkAW, const float* __restrict__ dW,
    const float* __restrict__ z0buf, const float* __restrict__ axbuf,
    const unsigned short* __restrict__ pk1, const unsigned short* __restrict__ pk2,
    const unsigned short* __restrict__ pk3,
    const float* __restrict__ fb1, const float* __restrict__ hb1,
    const float* __restrict__ fb2, const float* __restrict__ hb2,
    const float* __restrict__ fb3, const float* __restrict__ hb3,
    const float* __restrict__ gtab, float* __restrict__ z_all, float* __restrict__ rowlr)
{
    __shared__ __align__(16) unsigned short ybfA[1024];        // 2 KB drift input y (bf16, swizzled)
    __shared__ __align__(16) unsigned short ybfZ[1024];        // 2 KB z state (bf16, swizzled)
    __shared__ __align__(16) unsigned short o1[2][4096];       // 16 KB
    __shared__ __align__(16) unsigned short o2[2][4096];       // 16 KB
    __shared__ float fh2[2][2][16][64];                        // 16 KB (net, k-half)
    __shared__ float zcS[16][64];                              // 4 KB (z_enc out)

    int tid = threadIdx.x;
    int wv = tid >> 6;               // 0..15
    int lane = tid & 63;
    int rA = lane & 15, kg = lane >> 4;
    int sw = (rA & 7) << 3;
    int r_base = blockIdx.x * RPB;
    int e = blockIdx.x / 5;          // 5 blocks per e

    int net = wv >> 3;               // stage a/b net
    int na = (wv & 7) << 1;          // stage a/b n-tile base (2 tiles)
    int cnet = wv >> 3, crem = wv & 7, n0c = crem >> 1, khc = crem & 1;  // stage c (K-split)
    int nZ = wv & 3;                 // z_enc tile (waves 0-3)
    int lZ = (nZ << 4) + rA;         // z_enc col

    // ---- register-resident weights
    bf16x8 W0r0 = {}, W0r1 = {}, W1r[4], W2r[16], W3r[4];
    if (wv < 4) {
        const bf16x8* p0 = (const bf16x8*)pkAW + (e << 9);
        W0r0 = p0[(nZ * 2 + 0) * 64 + lane];
        W0r1 = p0[(nZ * 2 + 1) * 64 + lane];
    }
    {
        const bf16x8* p1 = (const bf16x8*)pk1 + net * 2048;
        #pragma unroll
        for (int f = 0; f < 4; ++f)
            W1r[f] = p1[((na + (f >> 1)) * 2 + (f & 1)) * 64 + lane];
        const bf16x8* p2 = (const bf16x8*)pk2 + net * 8192;
        #pragma unroll
        for (int i2 = 0; i2 < 2; ++i2)
            #pragma unroll
            for (int kc = 0; kc < 8; ++kc)
                W2r[i2 * 8 + kc] = p2[((na + i2) * 8 + kc) * 64 + lane];
        const bf16x8* p3 = (const bf16x8*)pk3 + cnet * 2048;
        #pragma unroll
        for (int kc = 0; kc < 4; ++kc)
            W3r[kc] = p3[(n0c * 8 + khc * 4 + kc) * 64 + lane];
    }
    float biasA0, biasA1, biasB0, biasB1, biasC;
    {
        const float* b1 = net ? hb1 : fb1;
        const float* b2 = net ? hb2 : fb2;
        const float* b3 = cnet ? hb3 : fb3;
        biasA0 = b1[((na + 0) << 4) + rA];
        biasA1 = b1[((na + 1) << 4) + rA];
        biasB0 = b2[((na + 0) << 4) + rA];
        biasB1 = b2[((na + 1) << 4) + rA];
        biasC = khc ? 0.f : b3[(n0c << 4) + rA];
    }

    // ---- owner state (tid < 640: orow = tid>>6, ol = tid&63)
    int orow = tid >> 6, ol = tid & 63;
    bool owner = (tid < RPB * L);
    float zc_r = 0.f, zh_r = 0.f, fz_r = 0.f, gz_r = 1.f;
    float dwA_r = 0.f, dwB_r = 0.f;
    float gt0 = 1.f, gt1 = 1.f, gfr = 0.f;
    float scal = 0.f;

    // ---- init ybfZ from z0 (rows >= RPB zeroed, stay zero forever)
    {
        int r = tid >> 6;
        float v = (tid < RPB * L) ? z0buf[(size_t)r_base * L + tid] : 0.f;
        ybfZ[tid ^ ((r & 7) << 3)] = f2bf(v);
    }
    __syncthreads();

    auto gprep = [&](float v) {
        float x = (v - GYMIN) * GINVDY;
        x = fminf(fmaxf(x, 0.0f), (float)(GNT - 2) + 0.999f);
        int ii = (int)x;
        gfr = x - (float)ii;
        const float* tl = gtab + ((size_t)ol << 12);
        gt0 = tl[ii];
        gt1 = tl[ii + 1];
    };

    for (int t = 0; t < T; ++t) {
        // ---- PZ: z_enc (waves 0-3): MFMA + ax (C-layout) -> ybfA + zcS
        if (wv < 4) {
            float axv[4];
            #pragma unroll
            for (int rr = 0; rr < 4; ++rr) {
                int r = (kg << 2) + rr;
                axv[rr] = (r < RPB) ? axbuf[((size_t)t * RTOT + r_base + r) * L + lZ] : 0.f;
            }
            bf16x8 Z0 = *(const bf16x8*)&ybfZ[((rA << 6) + (kg << 3)) ^ sw];
            bf16x8 Z1 = *(const bf16x8*)&ybfZ[((rA << 6) + 32 + (kg << 3)) ^ sw];
            f32x4 acc = (f32x4){0.f, 0.f, 0.f, 0.f};
            acc = MFMA16(Z0, W0r0, acc);
            acc = MFMA16(Z1, W0r1, acc);
            #pragma unroll
            for (int rr = 0; rr < 4; ++rr) {
                int r = (kg << 2) + rr;
                float v = acc[rr] + axv[rr];
                zcS[r][lZ] = v;
                ybfA[((r << 6) + lZ) ^ ((r & 7) << 3)] = f2bf(v);
            }
        }
        bar_lgkm();

        #pragma unroll
        for (int d = 0; d < 3; ++d) {
            // ---- Pa: y[16][64] @ W1 (regs) -> o1 ; owners prefetch at d==0
            if (d == 0 && owner) {
                zc_r = zcS[orow][ol];
                zh_r = zc_r;
                gprep(zc_r);
                dwA_r = dW[((size_t)(2 * t) * RTOT + r_base + orow) * L + ol] * SQDT;
                dwB_r = dW[((size_t)(2 * t + 1) * RTOT + r_base + orow) * L + ol] * SQDT;
            }
            {
                bf16x8 A0 = *(const bf16x8*)&ybfA[((rA << 6) + (kg << 3)) ^ sw];
                bf16x8 A1 = *(const bf16x8*)&ybfA[((rA << 6) + 32 + (kg << 3)) ^ sw];
                f32x4 acc0 = (f32x4){biasA0, biasA0, biasA0, biasA0};
                f32x4 acc1 = (f32x4){biasA1, biasA1, biasA1, biasA1};
                __builtin_amdgcn_s_setprio(1);
                acc0 = MFMA16(A0, W1r[0], acc0);
                acc0 = MFMA16(A1, W1r[1], acc0);
                acc1 = MFMA16(A0, W1r[2], acc1);
                acc1 = MFMA16(A1, W1r[3], acc1);
                __builtin_amdgcn_s_setprio(0);
                unsigned short* o1n = o1[net];
                int c0 = ((na + 0) << 4) + rA;
                int c1 = ((na + 1) << 4) + rA;
                #pragma unroll
                for (int rr = 0; rr < 4; ++rr) {
                    int r = (kg << 2) + rr;
                    int rx = (r & 7) << 3;
                    o1n[((r << 8) + c0) ^ rx] = f2bf(sigf(acc0[rr]));
                    o1n[((r << 8) + c1) ^ rx] = f2bf(sigf(acc1[rr]));
                }
            }
            bar_lgkm();
            // ---- Pb: h1[16][256] @ W2 (regs) -> o2
            {
                const unsigned short* o1n = o1[net];
                f32x4 acc0 = (f32x4){biasB0, biasB0, biasB0, biasB0};
                f32x4 acc1 = (f32x4){biasB1, biasB1, biasB1, biasB1};
                __builtin_amdgcn_s_setprio(1);
                #pragma unroll
                for (int kc = 0; kc < 8; ++kc) {
                    bf16x8 Ak = *(const bf16x8*)&o1n[((rA << 8) + (kc << 5) + (kg << 3)) ^ sw];
                    acc0 = MFMA16(Ak, W2r[kc], acc0);
                    acc1 = MFMA16(Ak, W2r[8 + kc], acc1);
                }
                __builtin_amdgcn_s_setprio(0);
                unsigned short* o2n = o2[net];
                int c0 = ((na + 0) << 4) + rA;
                int c1 = ((na + 1) << 4) + rA;
                #pragma unroll
                for (int rr = 0; rr < 4; ++rr) {
                    int r = (kg << 2) + rr;
                    int rx = (r & 7) << 3;
                    o2n[((r << 8) + c0) ^ rx] = f2bf(sigf(acc0[rr]));
                    o2n[((r << 8) + c1) ^ rx] = f2bf(sigf(acc1[rr]));
                }
            }
            bar_lgkm();
            // ---- Pc: h2[16][256] @ W3 (regs), K-split across wave pairs -> fh2
            {
                const unsigned short* o2n = o2[cnet];
                f32x4 acc = (f32x4){biasC, biasC, biasC, biasC};
                __builtin_amdgcn_s_setprio(1);
                #pragma unroll
                for (int kc = 0; kc < 4; ++kc) {
                    bf16x8 Ak = *(const bf16x8*)&o2n[((rA << 8) + (((khc << 2) + kc) << 5) + (kg << 3)) ^ sw];
                    acc = MFMA16(Ak, W3r[kc], acc);
                }
                __builtin_amdgcn_s_setprio(0);
                int c = (n0c << 4) + rA;
                #pragma unroll
                for (int rr = 0; rr < 4; ++rr)
                    fh2[cnet][khc][(kg << 2) + rr][c] = acc[rr];
            }
            bar_lgkm();
            // ---- Pf: finalize + Heun update in owner registers
            if (owner) {
                float fv = fh2[0][0][orow][ol] + fh2[0][1][orow][ol];
                float hv = fh2[1][0][orow][ol] + fh2[1][1][orow][ol];
                float gv = gt0 * (1.0f - gfr) + gt1 * gfr;
                float uu = (fv - hv) / gv;
                float us = uu * uu;
                if (d == 0) {
                    scal += us;
                    fz_r = fv; gz_r = gv;
                    float y1 = zc_r + fv * DT + gv * dwA_r;
                    zh_r = y1;
                    ybfA[tid ^ ((orow & 7) << 3)] = f2bf(y1);
                    gprep(y1);
                } else if (d == 1) {
                    zc_r += 0.5f * (fz_r + fv) * DT + 0.5f * (gz_r + gv) * dwA_r;
                    scal += 2.0f * us;
                    float y2 = 2.f * zc_r - zh_r + fv * DT + gv * dwB_r;
                    fz_r = fv; gz_r = gv;
                    ybfA[tid ^ ((orow & 7) << 3)] = f2bf(y2);
                    gprep(y2);
                } else {
                    zc_r += 0.5f * (fz_r + fv) * DT + 0.5f * (gz_r + gv) * dwB_r;
                    scal += us;
                    z_all[((size_t)t * RTOT + r_base) * L + tid] = zc_r;
                    ybfZ[tid ^ ((orow & 7) << 3)] = f2bf(zc_r);
                }
            }
            bar_lgkm();
        }
    }
    // ---- final KL reduction: rowlr[r] = 0.25*DT * sum_l scal(r,l)
    if (owner) {
        float s = scal;
        #pragma unroll
        for (int off = 32; off; off >>= 1) s += __shfl_xor(s, off);
        if (ol == 0) rowlr[r_base + orow] = 0.25f * DT * s;
    }
}

// ---------------------------------------------------------------- projection
__global__ __launch_bounds__(256) void proj_kernel(const float* __restrict__ z_all,
                            const float* __restrict__ pw1, const float* __restrict__ pb1,
                            const float* __restrict__ pw2, const float* __restrict__ pb2,
                            const float* __restrict__ pw3, const float* __restrict__ pb3,
                            float* __restrict__ out) {
    int bid = blockIdx.x;            // (t*E + e)*NBG + bg
    int bg = bid % NBG; int te = bid / NBG; int e = te % E; int t = te / E;
    int tid = threadIdx.x;           // 256
    __shared__ float zs[BGRP][L];
    __shared__ float p1s[BGRP][H];
    __shared__ float p2s[BGRP][H];
    __shared__ float part3[D][BGRP];
    size_t rbase = (size_t)t * RTOT + e * B + bg * BGRP;
    for (int i = tid; i < BGRP * L; i += 256) {
        int j = i >> 6, ll = i & 63;
        zs[j][ll] = z_all[(rbase + j) * L + ll];
    }
    __syncthreads();
    {
        float bias = pb1[e * H + tid];
        float acc[BGRP];
        #pragma unroll
        for (int j = 0; j < BGRP; ++j) acc[j] = bias;
        const float* w = pw1 + (size_t)e * L * H + tid;
        #pragma unroll 4
        for (int k = 0; k < L; ++k) {
            float wv = w[(size_t)k * H];
            #pragma unroll
            for (int j = 0; j < BGRP; ++j) acc[j] += zs[j][k] * wv;
        }
        #pragma unroll
        for (int j = 0; j < BGRP; ++j) p1s[j][tid] = sigf(acc[j]);
    }
    __syncthreads();
    {
        float bias = pb2[e * H + tid];
        float acc[BGRP];
        #pragma unroll
        for (int j = 0; j < BGRP; ++j) acc[j] = bias;
        const float* w = pw2 + (size_t)e * H * H + tid;
        #pragma unroll 4
        for (int k = 0; k < H; ++k) {
            float wv = w[(size_t)k * H];
            #pragma unroll
            for (int j = 0; j < BGRP; ++j) acc[j] += p1s[j][k] * wv;
        }
        #pragma unroll
        for (int j = 0; j < BGRP; ++j) p2s[j][tid] = sigf(acc[j]);
    }
    __syncthreads();
    float acc3[BGRP];
    {
        int dd = tid & 127, kh = tid >> 7;
        #pragma unroll
        for (int j = 0; j < BGRP; ++j) acc3[j] = 0.f;
        const float* w = pw3 + (size_t)e * H * D + dd;
        #pragma unroll 4
        for (int k = kh * 128; k < kh * 128 + 128; ++k) {
            float wv = w[(size_t)k * D];
            #pragma unroll
            for (int j = 0; j < BGRP; ++j) acc3[j] += p2s[j][k] * wv;
        }
        if (kh == 1) {
            #pragma unroll
            for (int j = 0; j < BGRP; ++j) part3[dd][j] = acc3[j];
        }
    }
    __syncthreads();
    if (tid < D) {
        float bias = pb3[e * D + tid];
        #pragma unroll
        for (int j = 0; j < BGRP; ++j) {
            out[8 + ((size_t)e * S + (size_t)t * B + bg * BGRP + j) * D + tid]
                = acc3[j] + part3[tid][j] + bias;
        }
    }
}

// ---------------------------------------------------------------- final combine
__global__ void fin_kernel(const float* __restrict__ logqp0p, const float* __restrict__ rowlr,
                           float* __restrict__ out) {
    int e = threadIdx.x;
    if (e < E) {
        float acc = 0.f;
        for (int t = 0; t < T; ++t)
            for (int bg = 0; bg < NBG; ++bg)
                acc += logqp0p[(t * E + e) * NBG + bg];
        float s = 0.f;
        for (int b = 0; b < B; ++b) s += rowlr[e * B + b];
        out[e] = acc + s / (float)B;
    }
}

extern "C" void kernel_launch(void* const* d_in, const int* in_sizes, int n_in,
                              void* d_out, int out_size, void* d_ws, size_t ws_size,
                              hipStream_t stream) {
    const float* xs      = (const float*)d_in[0];
    const float* actions = (const float*)d_in[1];
    const float* z0n     = (const float*)d_in[2];
    const float* dWp     = (const float*)d_in[3];
    const float* ew1     = (const float*)d_in[4];
    const float* eb1     = (const float*)d_in[5];
    const float* ew2     = (const float*)d_in[6];
    const float* eb2     = (const float*)d_in[7];
    const float* qw      = (const float*)d_in[8];
    const float* qb      = (const float*)d_in[9];
    const float* aw      = (const float*)d_in[10];
    const float* ab      = (const float*)d_in[11];
    const float* fw1     = (const float*)d_in[12];
    const float* fb1     = (const float*)d_in[13];
    const float* fw2     = (const float*)d_in[14];
    const float* fb2     = (const float*)d_in[15];
    const float* fw3     = (const float*)d_in[16];
    const float* fb3     = (const float*)d_in[17];
    const float* hw1     = (const float*)d_in[18];
    const float* hb1     = (const float*)d_in[19];
    const float* hw2     = (const float*)d_in[20];
    const float* hb2     = (const float*)d_in[21];
    const float* hw3     = (const float*)d_in[22];
    const float* hb3     = (const float*)d_in[23];
    const float* gw1     = (const float*)d_in[24];
    const float* gb1     = (const float*)d_in[25];
    const float* gw2     = (const float*)d_in[26];
    const float* gb2     = (const float*)d_in[27];
    const float* pw1     = (const float*)d_in[28];
    const float* pb1     = (const float*)d_in[29];
    const float* pw2     = (const float*)d_in[30];
    const float* pb2     = (const float*)d_in[31];
    const float* pw3     = (const float*)d_in[32];
    const float* pb3     = (const float*)d_in[33];
    const float* pm      = (const float*)d_in[34];
    const float* pl      = (const float*)d_in[35];

    float* ws      = (float*)d_ws;
    float* z0buf   = ws;                       // 25600
    float* axbuf   = z0buf + 25600;            // 3072000
    float* z_all   = axbuf + 3072000;          // 3072000
    float* logqp0p = z_all + 3072000;          // 4800
    float* rowlr   = logqp0p + 4800;           // 400
    float* gtab    = rowlr + 400;              // 262144
    unsigned short* pku = (unsigned short*)(gtab + 262144);
    unsigned short* pk1 = pku;                 // 2*16384
    unsigned short* pk2 = pk1 + 32768;         // 2*65536
    unsigned short* pk3 = pk2 + 131072;        // 2*16384
    unsigned short* pkAW = pk3 + 32768;        // E*4096
    float* out     = (float*)d_out;

    packB_kernel<<<64,  256, 0, stream>>>(fw1, pk1,          64, 256);
    packB_kernel<<<64,  256, 0, stream>>>(hw1, pk1 + 16384,  64, 256);
    packB_kernel<<<256, 256, 0, stream>>>(fw2, pk2,          256, 256);
    packB_kernel<<<256, 256, 0, stream>>>(hw2, pk2 + 65536,  256, 256);
    packB_kernel<<<64,  256, 0, stream>>>(fw3, pk3,          256, 64);
    packB_kernel<<<64,  256, 0, stream>>>(hw3, pk3 + 16384,  256, 64);
    packAW_kernel<<<128, 256, 0, stream>>>(aw, pkAW);
    gtab_kernel<<<1024, 256, 0, stream>>>(gw1, gb1, gw2, gb2, gtab);
    enc_kernel<<<T * E * NBG, 256, 0, stream>>>(xs, z0n, ew1, eb1, ew2, eb2, qw, qb, pm, pl, z0buf, logqp0p);
    ax_kernel<<<T * E * NBG, 64, 0, stream>>>(xs, actions, aw, ab, axbuf);
    seq_kernel<<<NBLK, 1024, 0, stream>>>(pkAW, dWp, z0buf, axbuf,
                                          pk1, pk2, pk3,
                                          fb1, hb1, fb2, hb2, fb3, hb3,
                                          gtab, z_all, rowlr);
    proj_kernel<<<T * E * NBG, 256, 0, stream>>>(z_all, pw1, pb1, pw2, pb2, pw3, pb3, out);
    fin_kernel<<<1, 64, 0, stream>>>(logqp0p, rowlr, out);
}

// Round 9
// 3335.564 us; speedup vs baseline: 1.0182x; 1.0182x over previous
//
#include <hip/hip_runtime.h>
#include <math.h>

#define E 8
#define S 6000
#define D 128
#define A 16
#define L 64
#define H 256
#define C 64
#define B 50
#define T 120
#define NSUB 2
#define FLAT 208      // L + A + D
#define RTOT 400      // E * B
#define RPB 10
#define NBLK (RTOT / RPB)   // 40, 5 blocks per e
#define BGRP 10
#define NBG 5

#define DT 0.5f
#define SQDT 0.70710678118654752440f

#define GNT 4096
#define GYMIN (-128.0f)
#define GDY 0.0625f
#define GINVDY 16.0f

typedef __attribute__((ext_vector_type(8))) short bf16x8;
typedef __attribute__((ext_vector_type(4))) float f32x4;

#define MFMA16(a, b, c) __builtin_amdgcn_mfma_f32_16x16x32_bf16(a, b, c, 0, 0, 0)

__device__ __forceinline__ float sigf(float x) {
    return __builtin_amdgcn_rcpf(1.0f + __expf(-x));
}

__device__ __forceinline__ unsigned short f2bf(float x) {
    union { float f; unsigned u; } v; v.f = x;
    return (unsigned short)((v.u + 0x8000u) >> 16);
}

__device__ __forceinline__ uint2 pack4(float v0, float v1, float v2, float v3) {
    uint2 w;
    w.x = (unsigned)f2bf(v0) | ((unsigned)f2bf(v1) << 16);
    w.y = (unsigned)f2bf(v2) | ((unsigned)f2bf(v3) << 16);
    return w;
}

// 4x4 transpose across lanes differing in bits 0-1 (m = lane&3).
// In: a_j = element (row_base + j) of column (col_base + m).
// Out: a_j = element (col_base + j) of row (row_base + m)  [verified mapping]
__device__ __forceinline__ void xpose4(float& a0, float& a1, float& a2, float& a3, int m) {
    float x0 = __shfl_xor(a0, 2), x1 = __shfl_xor(a1, 2);
    float x2 = __shfl_xor(a2, 2), x3 = __shfl_xor(a3, 2);
    bool hi = (m & 2);
    float b0 = hi ? x2 : a0;
    float b1 = hi ? x3 : a1;
    float b2 = hi ? a2 : x0;
    float b3 = hi ? a3 : x1;
    float y0 = __shfl_xor(b0, 1), y1 = __shfl_xor(b1, 1);
    float y2 = __shfl_xor(b2, 1), y3 = __shfl_xor(b3, 1);
    bool od = (m & 1);
    a0 = od ? y1 : b0;
    a1 = od ? b1 : y0;
    a2 = od ? y3 : b2;
    a3 = od ? b3 : y2;
}

// barrier that waits only LDS (lgkm); global loads stay in flight
__device__ __forceinline__ void bar_lgkm() {
    asm volatile("s_waitcnt lgkmcnt(0)" ::: "memory");
    __builtin_amdgcn_s_barrier();
}

// ---------------------------------------------------------------- g table
__global__ void gtab_kernel(const float* __restrict__ gw1, const float* __restrict__ gb1,
                            const float* __restrict__ gw2, const float* __restrict__ gb2,
                            float* __restrict__ tab) {
    int idx = blockIdx.x * blockDim.x + threadIdx.x;
    if (idx >= L * GNT) return;
    int l = idx / GNT, i = idx % GNT;
    float y = GYMIN + (float)i * GDY;
    const float* w1 = gw1 + l * H;
    const float* b1 = gb1 + l * H;
    const float* w2 = gw2 + l * H;
    float acc = gb2[l];
    #pragma unroll 4
    for (int h = 0; h < H; ++h) acc += w2[h] * (1.0f / (1.0f + __expf(-(y * w1[h] + b1[h]))));
    tab[idx] = acc;
}

// ---------------------------------------------------------------- B-fragment pack (bf16)
__global__ void packB_kernel(const float* __restrict__ src, unsigned short* __restrict__ dst,
                             int K, int N) {
    int idx = blockIdx.x * 256 + threadIdx.x;
    if (idx >= K * N) return;
    int j = idx & 7;
    int lane = (idx >> 3) & 63;
    int t2 = idx >> 9;               // n*(K/32) + kc
    int KC = K >> 5;
    int kc = t2 % KC, n = t2 / KC;
    int k = (kc << 5) + ((lane >> 4) << 3) + j;
    int c = (n << 4) + (lane & 15);
    union { float f; unsigned u; } v; v.f = src[k * N + c];
    dst[idx] = (unsigned short)((v.u + 0x7FFFu + ((v.u >> 16) & 1u)) >> 16);
}

// act_w z-rows per e -> bf16 fragments
__global__ void packAW_kernel(const float* __restrict__ aw, unsigned short* __restrict__ dst) {
    int idx = blockIdx.x * 256 + threadIdx.x;
    if (idx >= E * L * L) return;
    int e = idx >> 12;
    int rem = idx & 4095;
    int j = rem & 7;
    int lane = (rem >> 3) & 63;
    int t2 = rem >> 9;               // n*2 + kc
    int kc = t2 & 1, n = t2 >> 1;
    int k = (kc << 5) + ((lane >> 4) << 3) + j;
    int c = (n << 4) + (lane & 15);
    union { float f; unsigned u; } v; v.f = aw[((size_t)e * FLAT + k) * L + c];
    dst[idx] = (unsigned short)((v.u + 0x7FFFu + ((v.u >> 16) & 1u)) >> 16);
}

// ---------------------------------------------------------------- encoder + KL (+ z0 at t=0)
__global__ __launch_bounds__(256) void enc_kernel(const float* __restrict__ xs, const float* __restrict__ z0n,
                           const float* __restrict__ ew1, const float* __restrict__ eb1,
                           const float* __restrict__ ew2, const float* __restrict__ eb2,
                           const float* __restrict__ qw,  const float* __restrict__ qb,
                           const float* __restrict__ pm,  const float* __restrict__ pl,
                           float* __restrict__ z0buf, float* __restrict__ logqp0p) {
    int bid = blockIdx.x;            // (t*E + e)*NBG + bg
    int bg = bid % NBG; int te = bid / NBG; int e = te % E; int t = te / E;
    int tid = threadIdx.x;           // 256
    __shared__ float xsh[BGRP][D];
    __shared__ float c1s[BGRP][H];
    __shared__ float part[4][C][BGRP];
    __shared__ float ctxs[BGRP][C];
    __shared__ float qs[BGRP][2 * L];

    for (int i = tid; i < BGRP * D; i += 256) {
        int j = i / D, d = i % D;
        xsh[j][d] = xs[((size_t)e * S + (size_t)t * B + bg * BGRP + j) * D + d];
    }
    __syncthreads();
    {
        float bias = eb1[e * H + tid];
        float acc[BGRP];
        #pragma unroll
        for (int j = 0; j < BGRP; ++j) acc[j] = bias;
        const float* w = ew1 + (size_t)e * D * H + tid;
        #pragma unroll 4
        for (int d = 0; d < D; ++d) {
            float wv = w[(size_t)d * H];
            #pragma unroll
            for (int j = 0; j < BGRP; ++j) acc[j] += xsh[j][d] * wv;
        }
        #pragma unroll
        for (int j = 0; j < BGRP; ++j) c1s[j][tid] = sigf(acc[j]);
    }
    __syncthreads();
    {
        int c = tid & 63, kq = tid >> 6;
        float acc[BGRP];
        #pragma unroll
        for (int j = 0; j < BGRP; ++j) acc[j] = 0.f;
        const float* w = ew2 + (size_t)e * H * C + c;
        #pragma unroll 4
        for (int h = kq * 64; h < kq * 64 + 64; ++h) {
            float wv = w[(size_t)h * C];
            #pragma unroll
            for (int j = 0; j < BGRP; ++j) acc[j] += c1s[j][h] * wv;
        }
        #pragma unroll
        for (int j = 0; j < BGRP; ++j) part[kq][c][j] = acc[j];
    }
    __syncthreads();
    if (tid < C) {
        float bias = eb2[e * C + tid];
        #pragma unroll
        for (int j = 0; j < BGRP; ++j)
            ctxs[j][tid] = part[0][tid][j] + part[1][tid][j] + part[2][tid][j] + part[3][tid][j] + bias;
    }
    __syncthreads();
    if (tid < 2 * L) {
        float bias = qb[e * 2 * L + tid];
        float acc[BGRP];
        #pragma unroll
        for (int j = 0; j < BGRP; ++j) acc[j] = bias;
        const float* w = qw + (size_t)e * C * 2 * L + tid;
        #pragma unroll 4
        for (int c = 0; c < C; ++c) {
            float wv = w[(size_t)c * 2 * L];
            #pragma unroll
            for (int j = 0; j < BGRP; ++j) acc[j] += ctxs[j][c] * wv;
        }
        #pragma unroll
        for (int j = 0; j < BGRP; ++j) qs[j][tid] = acc[j];
    }
    __syncthreads();
    if (tid < L) {
        int l = tid;
        float kacc = 0.f;
        float m = pm[e * L + l], ls = pl[e * L + l];
        float inv2e = 1.0f / (2.0f * __expf(2.0f * ls));
        #pragma unroll
        for (int j = 0; j < BGRP; ++j) {
            float qm = qs[j][l], ql = qs[j][L + l];
            if (t == 0) {
                int b = bg * BGRP + j;
                float n = z0n[((size_t)e * B + b) * L + l];
                z0buf[((size_t)e * B + b) * L + l] = qm + __expf(ql) * n;
            }
            float dq = qm - m;
            kacc += ls - ql + (__expf(2.f * ql) + dq * dq) * inv2e - 0.5f;
        }
        #pragma unroll
        for (int off = 32; off; off >>= 1) kacc += __shfl_xor(kacc, off);
        if (l == 0) logqp0p[bid] = kacc / (float)B;
    }
}

// ---------------------------------------------------------------- action/x part of z_enc
__global__ __launch_bounds__(64) void ax_kernel(const float* __restrict__ xs, const float* __restrict__ actions,
                          const float* __restrict__ aw, const float* __restrict__ ab,
                          float* __restrict__ ax) {
    int bid = blockIdx.x;            // (t*E + e)*NBG + bg
    int bg = bid % NBG; int te = bid / NBG; int e = te % E; int t = te / E;
    int tid = threadIdx.x;           // 64
    __shared__ float xrow[BGRP][D];
    __shared__ float arow[BGRP][A];
    for (int i = tid; i < BGRP * D; i += 64) {
        int j = i / D, d = i % D;
        xrow[j][d] = xs[((size_t)e * S + (size_t)t * B + bg * BGRP + j) * D + d];
    }
    for (int i = tid; i < BGRP * A; i += 64) {
        int j = i / A, a = i % A;
        arow[j][a] = actions[((size_t)e * S + (size_t)t * B + bg * BGRP + j) * A + a];
    }
    __syncthreads();
    int l = tid;
    float acc[BGRP];
    float bias = ab[e * L + l];
    #pragma unroll
    for (int j = 0; j < BGRP; ++j) acc[j] = bias;
    const float* awp = aw + ((size_t)e * FLAT + L) * L + l;
    #pragma unroll 4
    for (int a = 0; a < A; ++a) {
        float wv = awp[(size_t)a * L];
        #pragma unroll
        for (int j = 0; j < BGRP; ++j) acc[j] += arow[j][a] * wv;
    }
    const float* xwp = aw + ((size_t)e * FLAT + L + A) * L + l;
    #pragma unroll 4
    for (int d = 0; d < D; ++d) {
        float wv = xwp[(size_t)d * L];
        #pragma unroll
        for (int j = 0; j < BGRP; ++j) acc[j] += xrow[j][d] * wv;
    }
    size_t rbase = (size_t)t * RTOT + e * B + bg * BGRP;
    #pragma unroll
    for (int j = 0; j < BGRP; ++j) ax[(rbase + j) * L + l] = acc[j];
}

// ---------------------------------------------------------------- sequential SDE loop
// Packed LDS writes (b64/b128 via in-register 4x4 transpose); lgkm-only barriers;
// W1 in LDS (reg-cliff), W2/W3/W0 in regs; split MFMA dep chains; no setprio.
__global__ __launch_bounds__(1024, 1) void seq_kernel(
    const unsigned short* __restrict__ pkAW, const float* __restrict__ dW,
    const float* __restrict__ z0buf, const float* __restrict__ axbuf,
    const unsigned short* __restrict__ pk1, const unsigned short* __restrict__ pk2,
    const unsigned short* __restrict__ pk3,
    const float* __restrict__ fb1, const float* __restrict__ hb1,
    const float* __restrict__ fb2, const float* __restrict__ hb2,
    const float* __restrict__ fb3, const float* __restrict__ hb3,
    const float* __restrict__ gtab, float* __restrict__ z_all, float* __restrict__ rowlr)
{
    __shared__ __align__(16) bf16x8 w1L[4096];                 // 64 KB stage-a weights (both nets)
    __shared__ __align__(16) unsigned short ybfA[1024];        // 2 KB drift input y (bf16, swizzled)
    __shared__ __align__(16) unsigned short ybfZ[1024];        // 2 KB z state (bf16, swizzled)
    __shared__ __align__(16) unsigned short o1[2][4096];       // 16 KB
    __shared__ __align__(16) unsigned short o2[2][4096];       // 16 KB
    __shared__ __align__(16) float fhF[4096];                  // 16 KB [(net*2+khc)*1024 + swz(r,c)]
    __shared__ __align__(16) float zcF[1024];                  // 4 KB (z_enc out, swz(r,c))

    int tid = threadIdx.x;
    int wv = tid >> 6;               // 0..15
    int lane = tid & 63;
    int rA = lane & 15, kg = lane >> 4;
    int m4 = lane & 3, rAhi = (lane >> 2) & 3;
    int sw = (rA & 7) << 3;
    int r_base = blockIdx.x * RPB;
    int e = blockIdx.x / 5;          // 5 blocks per e

    for (int i = tid; i < 4096; i += 1024) w1L[i] = ((const bf16x8*)pk1)[i];

    int net = wv >> 3;               // stage a/b net
    int na = (wv & 7) << 1;          // stage a/b n-tile base (2 tiles)
    int cnet = wv >> 3, crem = wv & 7, n0c = crem >> 1, khc = crem & 1;  // stage c (K-split)
    int nZ = wv & 3;                 // z_enc tile (waves 0-3)
    int lZ = (nZ << 4) + rA;         // z_enc col

    // ---- register-resident weights
    bf16x8 W0r0 = {}, W0r1 = {}, W2r[16], W3r[4];
    if (wv < 4) {
        const bf16x8* p0 = (const bf16x8*)pkAW + (e << 9);
        W0r0 = p0[(nZ * 2 + 0) * 64 + lane];
        W0r1 = p0[(nZ * 2 + 1) * 64 + lane];
    }
    {
        const bf16x8* p2 = (const bf16x8*)pk2 + net * 8192;
        #pragma unroll
        for (int i2 = 0; i2 < 2; ++i2)
            #pragma unroll
            for (int kc = 0; kc < 8; ++kc)
                W2r[i2 * 8 + kc] = p2[((na + i2) * 8 + kc) * 64 + lane];
        const bf16x8* p3 = (const bf16x8*)pk3 + cnet * 2048;
        #pragma unroll
        for (int kc = 0; kc < 4; ++kc)
            W3r[kc] = p3[(n0c * 8 + khc * 4 + kc) * 64 + lane];
    }
    float biasA0, biasA1, biasB0, biasB1, biasC;
    {
        const float* b1 = net ? hb1 : fb1;
        const float* b2 = net ? hb2 : fb2;
        const float* b3 = cnet ? hb3 : fb3;
        biasA0 = b1[((na + 0) << 4) + rA];
        biasA1 = b1[((na + 1) << 4) + rA];
        biasB0 = b2[((na + 0) << 4) + rA];
        biasB1 = b2[((na + 1) << 4) + rA];
        biasC = khc ? 0.f : b3[(n0c << 4) + rA];
    }

    // ---- owner state (tid < 640: orow = tid>>6, ol = tid&63)
    int orow = tid >> 6, ol = tid & 63;
    bool owner = (tid < RPB * L);
    int oswz = ((orow << 6) + ol) ^ ((orow & 7) << 2);   // f32-array owner index
    float zc_r = 0.f, zh_r = 0.f, fz_r = 0.f, gz_r = 1.f;
    float dwA_r = 0.f, dwB_r = 0.f;
    float gt0 = 1.f, gt1 = 1.f, gfr = 0.f;
    float scal = 0.f;

    // ---- init ybfZ from z0 (rows >= RPB zeroed, stay zero forever)
    {
        int r = tid >> 6;
        float v = (tid < RPB * L) ? z0buf[(size_t)r_base * L + tid] : 0.f;
        ybfZ[tid ^ ((r & 7) << 3)] = f2bf(v);
    }
    __syncthreads();

    auto gprep = [&](float v) {
        float x = (v - GYMIN) * GINVDY;
        x = fminf(fmaxf(x, 0.0f), (float)(GNT - 2) + 0.999f);
        int ii = (int)x;
        gfr = x - (float)ii;
        const float* tl = gtab + ((size_t)ol << 12);
        gt0 = tl[ii];
        gt1 = tl[ii + 1];
    };

    for (int t = 0; t < T; ++t) {
        // ---- PZ: z_enc (waves 0-3): MFMA + ax -> zcF (b128) + ybfA (b64)
        if (wv < 4) {
            float axv[4];
            #pragma unroll
            for (int rr = 0; rr < 4; ++rr) {
                int r = (kg << 2) + rr;
                axv[rr] = (r < RPB) ? axbuf[((size_t)t * RTOT + r_base + r) * L + lZ] : 0.f;
            }
            bf16x8 Z0 = *(const bf16x8*)&ybfZ[((rA << 6) + (kg << 3)) ^ sw];
            bf16x8 Z1 = *(const bf16x8*)&ybfZ[((rA << 6) + 32 + (kg << 3)) ^ sw];
            f32x4 acc = (f32x4){0.f, 0.f, 0.f, 0.f};
            acc = MFMA16(Z0, W0r0, acc);
            acc = MFMA16(Z1, W0r1, acc);
            float v0 = acc[0] + axv[0], v1 = acc[1] + axv[1];
            float v2 = acc[2] + axv[2], v3 = acc[3] + axv[3];
            xpose4(v0, v1, v2, v3, m4);
            int r = (kg << 2) + m4;
            int cb = (nZ << 4) + (rAhi << 2);
            *(f32x4*)&zcF[((r << 6) + cb) ^ ((r & 7) << 2)] = (f32x4){v0, v1, v2, v3};
            *(uint2*)&ybfA[((r << 6) + cb) ^ ((r & 7) << 3)] = pack4(v0, v1, v2, v3);
        }
        bar_lgkm();

        #pragma unroll
        for (int d = 0; d < 3; ++d) {
            // ---- Pa: y[16][64] @ W1 (LDS) -> o1 ; owners prefetch at d==0
            if (d == 0 && owner) {
                zc_r = zcF[oswz];
                zh_r = zc_r;
                gprep(zc_r);
                dwA_r = dW[((size_t)(2 * t) * RTOT + r_base + orow) * L + ol] * SQDT;
                dwB_r = dW[((size_t)(2 * t + 1) * RTOT + r_base + orow) * L + ol] * SQDT;
            }
            {
                bf16x8 A0 = *(const bf16x8*)&ybfA[((rA << 6) + (kg << 3)) ^ sw];
                bf16x8 A1 = *(const bf16x8*)&ybfA[((rA << 6) + 32 + (kg << 3)) ^ sw];
                f32x4 acc0 = (f32x4){biasA0, biasA0, biasA0, biasA0};
                f32x4 acc1 = (f32x4){biasA1, biasA1, biasA1, biasA1};
                acc0 = MFMA16(A0, w1L[net * 2048 + ((na + 0) * 2 + 0) * 64 + lane], acc0);
                acc0 = MFMA16(A1, w1L[net * 2048 + ((na + 0) * 2 + 1) * 64 + lane], acc0);
                acc1 = MFMA16(A0, w1L[net * 2048 + ((na + 1) * 2 + 0) * 64 + lane], acc1);
                acc1 = MFMA16(A1, w1L[net * 2048 + ((na + 1) * 2 + 1) * 64 + lane], acc1);
                unsigned short* o1n = o1[net];
                int r = (kg << 2) + m4;
                #pragma unroll
                for (int i2 = 0; i2 < 2; ++i2) {
                    f32x4 a = i2 ? acc1 : acc0;
                    float s0 = sigf(a[0]), s1 = sigf(a[1]), s2 = sigf(a[2]), s3 = sigf(a[3]);
                    xpose4(s0, s1, s2, s3, m4);
                    int cb = ((na + i2) << 4) + (rAhi << 2);
                    *(uint2*)&o1n[((r << 8) + cb) ^ ((r & 7) << 3)] = pack4(s0, s1, s2, s3);
                }
            }
            bar_lgkm();
            // ---- Pb: h1[16][256] @ W2 (regs) -> o2  (split dep chains)
            {
                const unsigned short* o1n = o1[net];
                f32x4 acc0 = (f32x4){biasB0, biasB0, biasB0, biasB0};
                f32x4 acc1 = (f32x4){biasB1, biasB1, biasB1, biasB1};
                f32x4 acc0b = (f32x4){0.f, 0.f, 0.f, 0.f};
                f32x4 acc1b = (f32x4){0.f, 0.f, 0.f, 0.f};
                #pragma unroll
                for (int kc = 0; kc < 4; ++kc) {
                    bf16x8 Ak = *(const bf16x8*)&o1n[((rA << 8) + (kc << 5) + (kg << 3)) ^ sw];
                    acc0 = MFMA16(Ak, W2r[kc], acc0);
                    acc1 = MFMA16(Ak, W2r[8 + kc], acc1);
                }
                #pragma unroll
                for (int kc = 4; kc < 8; ++kc) {
                    bf16x8 Ak = *(const bf16x8*)&o1n[((rA << 8) + (kc << 5) + (kg << 3)) ^ sw];
                    acc0b = MFMA16(Ak, W2r[kc], acc0b);
                    acc1b = MFMA16(Ak, W2r[8 + kc], acc1b);
                }
                unsigned short* o2n = o2[net];
                int r = (kg << 2) + m4;
                #pragma unroll
                for (int i2 = 0; i2 < 2; ++i2) {
                    f32x4 a = i2 ? acc1 : acc0;
                    f32x4 b = i2 ? acc1b : acc0b;
                    float s0 = sigf(a[0] + b[0]), s1 = sigf(a[1] + b[1]);
                    float s2 = sigf(a[2] + b[2]), s3 = sigf(a[3] + b[3]);
                    xpose4(s0, s1, s2, s3, m4);
                    int cb = ((na + i2) << 4) + (rAhi << 2);
                    *(uint2*)&o2n[((r << 8) + cb) ^ ((r & 7) << 3)] = pack4(s0, s1, s2, s3);
                }
            }
            bar_lgkm();
            // ---- Pc: h2[16][256] @ W3 (regs), K-split across wave pairs -> fhF (b128)
            {
                const unsigned short* o2n = o2[cnet];
                f32x4 acc = (f32x4){biasC, biasC, biasC, biasC};
                f32x4 accb = (f32x4){0.f, 0.f, 0.f, 0.f};
                {
                    bf16x8 Ak0 = *(const bf16x8*)&o2n[((rA << 8) + (((khc << 2) + 0) << 5) + (kg << 3)) ^ sw];
                    bf16x8 Ak1 = *(const bf16x8*)&o2n[((rA << 8) + (((khc << 2) + 1) << 5) + (kg << 3)) ^ sw];
                    bf16x8 Ak2 = *(const bf16x8*)&o2n[((rA << 8) + (((khc << 2) + 2) << 5) + (kg << 3)) ^ sw];
                    bf16x8 Ak3 = *(const bf16x8*)&o2n[((rA << 8) + (((khc << 2) + 3) << 5) + (kg << 3)) ^ sw];
                    acc  = MFMA16(Ak0, W3r[0], acc);
                    accb = MFMA16(Ak1, W3r[1], accb);
                    acc  = MFMA16(Ak2, W3r[2], acc);
                    accb = MFMA16(Ak3, W3r[3], accb);
                }
                float v0 = acc[0] + accb[0], v1 = acc[1] + accb[1];
                float v2 = acc[2] + accb[2], v3 = acc[3] + accb[3];
                xpose4(v0, v1, v2, v3, m4);
                int r = (kg << 2) + m4;
                int cb = (n0c << 4) + (rAhi << 2);
                *(f32x4*)&fhF[(((cnet << 1) + khc) << 10) + (((r << 6) + cb) ^ ((r & 7) << 2))]
                    = (f32x4){v0, v1, v2, v3};
            }
            bar_lgkm();
            // ---- Pf: finalize + Heun update in owner registers
            if (owner) {
                float fv = fhF[oswz] + fhF[1024 + oswz];
                float hv = fhF[2048 + oswz] + fhF[3072 + oswz];
                float gv = gt0 * (1.0f - gfr) + gt1 * gfr;
                float uu = (fv - hv) / gv;
                float us = uu * uu;
                if (d == 0) {
                    scal += us;
                    fz_r = fv; gz_r = gv;
                    float y1 = zc_r + fv * DT + gv * dwA_r;
                    zh_r = y1;
                    ybfA[tid ^ ((orow & 7) << 3)] = f2bf(y1);
                    gprep(y1);
                } else if (d == 1) {
                    zc_r += 0.5f * (fz_r + fv) * DT + 0.5f * (gz_r + gv) * dwA_r;
                    scal += 2.0f * us;
                    float y2 = 2.f * zc_r - zh_r + fv * DT + gv * dwB_r;
                    fz_r = fv; gz_r = gv;
                    ybfA[tid ^ ((orow & 7) << 3)] = f2bf(y2);
                    gprep(y2);
                } else {
                    zc_r += 0.5f * (fz_r + fv) * DT + 0.5f * (gz_r + gv) * dwB_r;
                    scal += us;
                    z_all[((size_t)t * RTOT + r_base) * L + tid] = zc_r;
                    ybfZ[tid ^ ((orow & 7) << 3)] = f2bf(zc_r);
                }
            }
            bar_lgkm();
        }
    }
    // ---- final KL reduction: rowlr[r] = 0.25*DT * sum_l scal(r,l)
    if (owner) {
        float s = scal;
        #pragma unroll
        for (int off = 32; off; off >>= 1) s += __shfl_xor(s, off);
        if (ol == 0) rowlr[r_base + orow] = 0.25f * DT * s;
    }
}

// ---------------------------------------------------------------- projection
__global__ __launch_bounds__(256) void proj_kernel(const float* __restrict__ z_all,
                            const float* __restrict__ pw1, const float* __restrict__ pb1,
                            const float* __restrict__ pw2, const float* __restrict__ pb2,
                            const float* __restrict__ pw3, const float* __restrict__ pb3,
                            float* __restrict__ out) {
    int bid = blockIdx.x;            // (t*E + e)*NBG + bg
    int bg = bid % NBG; int te = bid / NBG; int e = te % E; int t = te / E;
    int tid = threadIdx.x;           // 256
    __shared__ float zs[BGRP][L];
    __shared__ float p1s[BGRP][H];
    __shared__ float p2s[BGRP][H];
    __shared__ float part3[D][BGRP];
    size_t rbase = (size_t)t * RTOT + e * B + bg * BGRP;
    for (int i = tid; i < BGRP * L; i += 256) {
        int j = i >> 6, ll = i & 63;
        zs[j][ll] = z_all[(rbase + j) * L + ll];
    }
    __syncthreads();
    {
        float bias = pb1[e * H + tid];
        float acc[BGRP];
        #pragma unroll
        for (int j = 0; j < BGRP; ++j) acc[j] = bias;
        const float* w = pw1 + (size_t)e * L * H + tid;
        #pragma unroll 4
        for (int k = 0; k < L; ++k) {
            float wv = w[(size_t)k * H];
            #pragma unroll
            for (int j = 0; j < BGRP; ++j) acc[j] += zs[j][k] * wv;
        }
        #pragma unroll
        for (int j = 0; j < BGRP; ++j) p1s[j][tid] = sigf(acc[j]);
    }
    __syncthreads();
    {
        float bias = pb2[e * H + tid];
        float acc[BGRP];
        #pragma unroll
        for (int j = 0; j < BGRP; ++j) acc[j] = bias;
        const float* w = pw2 + (size_t)e * H * H + tid;
        #pragma unroll 4
        for (int k = 0; k < H; ++k) {
            float wv = w[(size_t)k * H];
            #pragma unroll
            for (int j = 0; j < BGRP; ++j) acc[j] += p1s[j][k] * wv;
        }
        #pragma unroll
        for (int j = 0; j < BGRP; ++j) p2s[j][tid] = sigf(acc[j]);
    }
    __syncthreads();
    float acc3[BGRP];
    {
        int dd = tid & 127, kh = tid >> 7;
        #pragma unroll
        for (int j = 0; j < BGRP; ++j) acc3[j] = 0.f;
        const float* w = pw3 + (size_t)e * H * D + dd;
        #pragma unroll 4
        for (int k = kh * 128; k < kh * 128 + 128; ++k) {
            float wv = w[(size_t)k * D];
            #pragma unroll
            for (int j = 0; j < BGRP; ++j) acc3[j] += p2s[j][k] * wv;
        }
        if (kh == 1) {
            #pragma unroll
            for (int j = 0; j < BGRP; ++j) part3[dd][j] = acc3[j];
        }
    }
    __syncthreads();
    if (tid < D) {
        float bias = pb3[e * D + tid];
        #pragma unroll
        for (int j = 0; j < BGRP; ++j) {
            out[8 + ((size_t)e * S + (size_t)t * B + bg * BGRP + j) * D + tid]
                = acc3[j] + part3[tid][j] + bias;
        }
    }
}

// ---------------------------------------------------------------- final combine
__global__ void fin_kernel(const float* __restrict__ logqp0p, const float* __restrict__ rowlr,
                           float* __restrict__ out) {
    int e = threadIdx.x;
    if (e < E) {
        float acc = 0.f;
        for (int t = 0; t < T; ++t)
            for (int bg = 0; bg < NBG; ++bg)
                acc += logqp0p[(t * E + e) * NBG + bg];
        float s = 0.f;
        for (int b = 0; b < B; ++b) s += rowlr[e * B + b];
        out[e] = acc + s / (float)B;
    }
}

extern "C" void kernel_launch(void* const* d_in, const int* in_sizes, int n_in,
                              void* d_out, int out_size, void* d_ws, size_t ws_size,
                              hipStream_t stream) {
    const float* xs      = (const float*)d_in[0];
    const float* actions = (const float*)d_in[1];
    const float* z0n     = (const float*)d_in[2];
    const float* dWp     = (const float*)d_in[3];
    const float* ew1     = (const float*)d_in[4];
    const float* eb1     = (const float*)d_in[5];
    const float* ew2     = (const float*)d_in[6];
    const float* eb2     = (const float*)d_in[7];
    const float* qw      = (const float*)d_in[8];
    const float* qb      = (const float*)d_in[9];
    const float* aw      = (const float*)d_in[10];
    const float* ab      = (const float*)d_in[11];
    const float* fw1     = (const float*)d_in[12];
    const float* fb1     = (const float*)d_in[13];
    const float* fw2     = (const float*)d_in[14];
    const float* fb2     = (const float*)d_in[15];
    const float* fw3     = (const float*)d_in[16];
    const float* fb3     = (const float*)d_in[17];
    const float* hw1     = (const float*)d_in[18];
    const float* hb1     = (const float*)d_in[19];
    const float* hw2     = (const float*)d_in[20];
    const float* hb2     = (const float*)d_in[21];
    const float* hw3     = (const float*)d_in[22];
    const float* hb3     = (const float*)d_in[23];
    const float* gw1     = (const float*)d_in[24];
    const float* gb1     = (const float*)d_in[25];
    const float* gw2     = (const float*)d_in[26];
    const float* gb2     = (const float*)d_in[27];
    const float* pw1     = (const float*)d_in[28];
    const float* pb1     = (const float*)d_in[29];
    const float* pw2     = (const float*)d_in[30];
    const float* pb2     = (const float*)d_in[31];
    const float* pw3     = (const float*)d_in[32];
    const float* pb3     = (const float*)d_in[33];
    const float* pm      = (const float*)d_in[34];
    const float* pl      = (const float*)d_in[35];

    float* ws      = (float*)d_ws;
    float* z0buf   = ws;                       // 25600
    float* axbuf   = z0buf + 25600;            // 3072000
    float* z_all   = axbuf + 3072000;          // 3072000
    float* logqp0p = z_all + 3072000;          // 4800
    float* rowlr   = logqp0p + 4800;           // 400
    float* gtab    = rowlr + 400;              // 262144
    unsigned short* pku = (unsigned short*)(gtab + 262144);
    unsigned short* pk1 = pku;                 // 2*16384
    unsigned short* pk2 = pk1 + 32768;         // 2*65536
    unsigned short* pk3 = pk2 + 131072;        // 2*16384
    unsigned short* pkAW = pk3 + 32768;        // E*4096
    float* out     = (float*)d_out;

    packB_kernel<<<64,  256, 0, stream>>>(fw1, pk1,          64, 256);
    packB_kernel<<<64,  256, 0, stream>>>(hw1, pk1 + 16384,  64, 256);
    packB_kernel<<<256, 256, 0, stream>>>(fw2, pk2,          256, 256);
    packB_kernel<<<256, 256, 0, stream>>>(hw2, pk2 + 65536,  256, 256);
    packB_kernel<<<64,  256, 0, stream>>>(fw3, pk3,          256, 64);
    packB_kernel<<<64,  256, 0, stream>>>(hw3, pk3 + 16384,  256, 64);
    packAW_kernel<<<128, 256, 0, stream>>>(aw, pkAW);
    gtab_kernel<<<1024, 256, 0, stream>>>(gw1, gb1, gw2, gb2, gtab);
    enc_kernel<<<T * E * NBG, 256, 0, stream>>>(xs, z0n, ew1, eb1, ew2, eb2, qw, qb, pm, pl, z0buf, logqp0p);
    ax_kernel<<<T * E * NBG, 64, 0, stream>>>(xs, actions, aw, ab, axbuf);
    seq_kernel<<<NBLK, 1024, 0, stream>>>(pkAW, dWp, z0buf, axbuf,
                                          pk1, pk2, pk3,
                                          fb1, hb1, fb2, hb2, fb3, hb3,
                                          gtab, z_all, rowlr);
    proj_kernel<<<T * E * NBG, 256, 0, stream>>>(z_all, pw1, pb1, pw2, pb2, pw3, pb3, out);
    fin_kernel<<<1, 64, 0, stream>>>(logqp0p, rowlr, out);
}

// Round 10
// 2615.447 us; speedup vs baseline: 1.2985x; 1.2753x over previous
//
#include <hip/hip_runtime.h>
#include <math.h>

#define E 8
#define S 6000
#define D 128
#define A 16
#define L 64
#define H 256
#define C 64
#define B 50
#define T 120
#define NSUB 2
#define FLAT 208      // L + A + D
#define RTOT 400      // E * B
#define RPB 10
#define NBLK (RTOT / RPB)   // 40, 5 blocks per e
#define BGRP 10
#define NBG 5

#define DT 0.5f
#define SQDT 0.70710678118654752440f

#define GNT 4096
#define GYMIN (-128.0f)
#define GDY 0.0625f
#define GINVDY 16.0f

typedef __attribute__((ext_vector_type(8))) short bf16x8;
typedef __attribute__((ext_vector_type(4))) float f32x4;

#define MFMA16(a, b, c) __builtin_amdgcn_mfma_f32_16x16x32_bf16(a, b, c, 0, 0, 0)

__device__ __forceinline__ float sigf(float x) {
    return __builtin_amdgcn_rcpf(1.0f + __expf(-x));
}

__device__ __forceinline__ unsigned short f2bf(float x) {
    union { float f; unsigned u; } v; v.f = x;
    return (unsigned short)((v.u + 0x8000u) >> 16);
}

// barrier that waits only LDS (lgkm); global loads stay in flight
__device__ __forceinline__ void bar_lgkm() {
    asm volatile("s_waitcnt lgkmcnt(0)" ::: "memory");
    __builtin_amdgcn_s_barrier();
}

// ---------------------------------------------------------------- g table
__global__ void gtab_kernel(const float* __restrict__ gw1, const float* __restrict__ gb1,
                            const float* __restrict__ gw2, const float* __restrict__ gb2,
                            float* __restrict__ tab) {
    int idx = blockIdx.x * blockDim.x + threadIdx.x;
    if (idx >= L * GNT) return;
    int l = idx / GNT, i = idx % GNT;
    float y = GYMIN + (float)i * GDY;
    const float* w1 = gw1 + l * H;
    const float* b1 = gb1 + l * H;
    const float* w2 = gw2 + l * H;
    float acc = gb2[l];
    #pragma unroll 4
    for (int h = 0; h < H; ++h) acc += w2[h] * (1.0f / (1.0f + __expf(-(y * w1[h] + b1[h]))));
    tab[idx] = acc;
}

// ---------------------------------------------------------------- B-fragment pack (bf16)
__global__ void packB_kernel(const float* __restrict__ src, unsigned short* __restrict__ dst,
                             int K, int N) {
    int idx = blockIdx.x * 256 + threadIdx.x;
    if (idx >= K * N) return;
    int j = idx & 7;
    int lane = (idx >> 3) & 63;
    int t2 = idx >> 9;               // n*(K/32) + kc
    int KC = K >> 5;
    int kc = t2 % KC, n = t2 / KC;
    int k = (kc << 5) + ((lane >> 4) << 3) + j;
    int c = (n << 4) + (lane & 15);
    union { float f; unsigned u; } v; v.f = src[k * N + c];
    dst[idx] = (unsigned short)((v.u + 0x7FFFu + ((v.u >> 16) & 1u)) >> 16);
}

// act_w z-rows per e -> bf16 fragments
__global__ void packAW_kernel(const float* __restrict__ aw, unsigned short* __restrict__ dst) {
    int idx = blockIdx.x * 256 + threadIdx.x;
    if (idx >= E * L * L) return;
    int e = idx >> 12;
    int rem = idx & 4095;
    int j = rem & 7;
    int lane = (rem >> 3) & 63;
    int t2 = rem >> 9;               // n*2 + kc
    int kc = t2 & 1, n = t2 >> 1;
    int k = (kc << 5) + ((lane >> 4) << 3) + j;
    int c = (n << 4) + (lane & 15);
    union { float f; unsigned u; } v; v.f = aw[((size_t)e * FLAT + k) * L + c];
    dst[idx] = (unsigned short)((v.u + 0x7FFFu + ((v.u >> 16) & 1u)) >> 16);
}

// ---------------------------------------------------------------- encoder + KL (+ z0 at t=0)
__global__ __launch_bounds__(256) void enc_kernel(const float* __restrict__ xs, const float* __restrict__ z0n,
                           const float* __restrict__ ew1, const float* __restrict__ eb1,
                           const float* __restrict__ ew2, const float* __restrict__ eb2,
                           const float* __restrict__ qw,  const float* __restrict__ qb,
                           const float* __restrict__ pm,  const float* __restrict__ pl,
                           float* __restrict__ z0buf, float* __restrict__ logqp0p) {
    int bid = blockIdx.x;            // (t*E + e)*NBG + bg
    int bg = bid % NBG; int te = bid / NBG; int e = te % E; int t = te / E;
    int tid = threadIdx.x;           // 256
    __shared__ float xsh[BGRP][D];
    __shared__ float c1s[BGRP][H];
    __shared__ float part[4][C][BGRP];
    __shared__ float ctxs[BGRP][C];
    __shared__ float qs[BGRP][2 * L];

    for (int i = tid; i < BGRP * D; i += 256) {
        int j = i / D, d = i % D;
        xsh[j][d] = xs[((size_t)e * S + (size_t)t * B + bg * BGRP + j) * D + d];
    }
    __syncthreads();
    {
        float bias = eb1[e * H + tid];
        float acc[BGRP];
        #pragma unroll
        for (int j = 0; j < BGRP; ++j) acc[j] = bias;
        const float* w = ew1 + (size_t)e * D * H + tid;
        #pragma unroll 4
        for (int d = 0; d < D; ++d) {
            float wv = w[(size_t)d * H];
            #pragma unroll
            for (int j = 0; j < BGRP; ++j) acc[j] += xsh[j][d] * wv;
        }
        #pragma unroll
        for (int j = 0; j < BGRP; ++j) c1s[j][tid] = sigf(acc[j]);
    }
    __syncthreads();
    {
        int c = tid & 63, kq = tid >> 6;
        float acc[BGRP];
        #pragma unroll
        for (int j = 0; j < BGRP; ++j) acc[j] = 0.f;
        const float* w = ew2 + (size_t)e * H * C + c;
        #pragma unroll 4
        for (int h = kq * 64; h < kq * 64 + 64; ++h) {
            float wv = w[(size_t)h * C];
            #pragma unroll
            for (int j = 0; j < BGRP; ++j) acc[j] += c1s[j][h] * wv;
        }
        #pragma unroll
        for (int j = 0; j < BGRP; ++j) part[kq][c][j] = acc[j];
    }
    __syncthreads();
    if (tid < C) {
        float bias = eb2[e * C + tid];
        #pragma unroll
        for (int j = 0; j < BGRP; ++j)
            ctxs[j][tid] = part[0][tid][j] + part[1][tid][j] + part[2][tid][j] + part[3][tid][j] + bias;
    }
    __syncthreads();
    if (tid < 2 * L) {
        float bias = qb[e * 2 * L + tid];
        float acc[BGRP];
        #pragma unroll
        for (int j = 0; j < BGRP; ++j) acc[j] = bias;
        const float* w = qw + (size_t)e * C * 2 * L + tid;
        #pragma unroll 4
        for (int c = 0; c < C; ++c) {
            float wv = w[(size_t)c * 2 * L];
            #pragma unroll
            for (int j = 0; j < BGRP; ++j) acc[j] += ctxs[j][c] * wv;
        }
        #pragma unroll
        for (int j = 0; j < BGRP; ++j) qs[j][tid] = acc[j];
    }
    __syncthreads();
    if (tid < L) {
        int l = tid;
        float kacc = 0.f;
        float m = pm[e * L + l], ls = pl[e * L + l];
        float inv2e = 1.0f / (2.0f * __expf(2.0f * ls));
        #pragma unroll
        for (int j = 0; j < BGRP; ++j) {
            float qm = qs[j][l], ql = qs[j][L + l];
            if (t == 0) {
                int b = bg * BGRP + j;
                float n = z0n[((size_t)e * B + b) * L + l];
                z0buf[((size_t)e * B + b) * L + l] = qm + __expf(ql) * n;
            }
            float dq = qm - m;
            kacc += ls - ql + (__expf(2.f * ql) + dq * dq) * inv2e - 0.5f;
        }
        #pragma unroll
        for (int off = 32; off; off >>= 1) kacc += __shfl_xor(kacc, off);
        if (l == 0) logqp0p[bid] = kacc / (float)B;
    }
}

// ---------------------------------------------------------------- action/x part of z_enc
__global__ __launch_bounds__(64) void ax_kernel(const float* __restrict__ xs, const float* __restrict__ actions,
                          const float* __restrict__ aw, const float* __restrict__ ab,
                          float* __restrict__ ax) {
    int bid = blockIdx.x;            // (t*E + e)*NBG + bg
    int bg = bid % NBG; int te = bid / NBG; int e = te % E; int t = te / E;
    int tid = threadIdx.x;           // 64
    __shared__ float xrow[BGRP][D];
    __shared__ float arow[BGRP][A];
    for (int i = tid; i < BGRP * D; i += 64) {
        int j = i / D, d = i % D;
        xrow[j][d] = xs[((size_t)e * S + (size_t)t * B + bg * BGRP + j) * D + d];
    }
    for (int i = tid; i < BGRP * A; i += 64) {
        int j = i / A, a = i % A;
        arow[j][a] = actions[((size_t)e * S + (size_t)t * B + bg * BGRP + j) * A + a];
    }
    __syncthreads();
    int l = tid;
    float acc[BGRP];
    float bias = ab[e * L + l];
    #pragma unroll
    for (int j = 0; j < BGRP; ++j) acc[j] = bias;
    const float* awp = aw + ((size_t)e * FLAT + L) * L + l;
    #pragma unroll 4
    for (int a = 0; a < A; ++a) {
        float wv = awp[(size_t)a * L];
        #pragma unroll
        for (int j = 0; j < BGRP; ++j) acc[j] += arow[j][a] * wv;
    }
    const float* xwp = aw + ((size_t)e * FLAT + L + A) * L + l;
    #pragma unroll 4
    for (int d = 0; d < D; ++d) {
        float wv = xwp[(size_t)d * L];
        #pragma unroll
        for (int j = 0; j < BGRP; ++j) acc[j] += xrow[j][d] * wv;
    }
    size_t rbase = (size_t)t * RTOT + e * B + bg * BGRP;
    #pragma unroll
    for (int j = 0; j < BGRP; ++j) ax[(rbase + j) * L + l] = acc[j];
}

// ---------------------------------------------------------------- sequential SDE loop
// 8 waves (512 threads): measured lowest per-phase cost. 13 phases/step.
// W1 in LDS; W2 (32 frags), W3 (8 frags), W0 (2 frags) in regs.
// Owners hold all SDE state in registers (dual-element for tid<128).
// d-loop NOT unrolled (I$ footprint). ax staged one step ahead via LDS.
__global__ __launch_bounds__(512, 2) void seq_kernel(
    const unsigned short* __restrict__ pkAW, const float* __restrict__ dW,
    const float* __restrict__ z0buf, const float* __restrict__ axbuf,
    const unsigned short* __restrict__ pk1, const unsigned short* __restrict__ pk2,
    const unsigned short* __restrict__ pk3,
    const float* __restrict__ fb1, const float* __restrict__ hb1,
    const float* __restrict__ fb2, const float* __restrict__ hb2,
    const float* __restrict__ fb3, const float* __restrict__ hb3,
    const float* __restrict__ gtab, float* __restrict__ z_all, float* __restrict__ rowlr)
{
    __shared__ __align__(16) bf16x8 w1L[4096];                 // 64 KB stage-a weights (both nets)
    __shared__ __align__(16) unsigned short ybfA[1024];        // 2 KB drift input y (bf16, swizzled)
    __shared__ __align__(16) unsigned short ybfZ[1024];        // 2 KB z state (bf16, swizzled)
    __shared__ __align__(16) unsigned short o1[2][4096];       // 16 KB
    __shared__ __align__(16) unsigned short o2[2][4096];       // 16 KB
    __shared__ float fh2[2][16][64];                           // 8 KB
    __shared__ float zcS[16][64];                              // 4 KB (z_enc out)
    __shared__ float axS[RPB * L];                             // 2.5 KB (ax staged 1 step ahead)

    int tid = threadIdx.x;
    int wv = tid >> 6;               // 0..7
    int lane = tid & 63;
    int rA = lane & 15, kg = lane >> 4;
    int sw = (rA & 7) << 3;
    int r_base = blockIdx.x * RPB;
    int e = blockIdx.x / 5;          // 5 blocks per e

    for (int i = tid; i < 4096; i += 512) w1L[i] = ((const bf16x8*)pk1)[i];

    int net = wv >> 2;               // 0..1
    int nq  = wv & 3;
    int na  = nq << 2;               // stage a/b: 4 n-tiles per wave
    int n0c = nq;                    // stage c tile (per net)
    int lZ = (nq << 4) + rA;         // z_enc col (waves 0-3)

    // ---- register-resident weights
    bf16x8 W0r0 = {}, W0r1 = {}, W2r[32], W3r[8];
    if (wv < 4) {
        const bf16x8* p0 = (const bf16x8*)pkAW + (e << 9);
        W0r0 = p0[(nq * 2 + 0) * 64 + lane];
        W0r1 = p0[(nq * 2 + 1) * 64 + lane];
    }
    {
        const bf16x8* p2 = (const bf16x8*)pk2 + net * 8192;
        #pragma unroll
        for (int i2 = 0; i2 < 4; ++i2)
            #pragma unroll
            for (int kc = 0; kc < 8; ++kc)
                W2r[i2 * 8 + kc] = p2[((na + i2) * 8 + kc) * 64 + lane];
        const bf16x8* p3 = (const bf16x8*)pk3 + net * 2048;
        #pragma unroll
        for (int kc = 0; kc < 8; ++kc)
            W3r[kc] = p3[(n0c * 8 + kc) * 64 + lane];
    }
    float biasA[4], biasB[4], biasC;
    {
        const float* b1 = net ? hb1 : fb1;
        const float* b2 = net ? hb2 : fb2;
        const float* b3 = net ? hb3 : fb3;
        #pragma unroll
        for (int i2 = 0; i2 < 4; ++i2) {
            biasA[i2] = b1[((na + i2) << 4) + rA];
            biasB[i2] = b2[((na + i2) << 4) + rA];
        }
        biasC = b3[(n0c << 4) + rA];
    }

    // ---- owner state: element tid (rows 0-7); tid<128 also owns 512+tid (rows 8-9)
    int orowA = tid >> 6, olA = tid & 63;
    bool ownB = (tid < RPB * L - 512);           // tid < 128
    int orowB = 8 + (tid >> 6);                  // valid when ownB
    float zcA = 0.f, zhA_ = 0.f, fzA = 0.f, gzA = 1.f, dwAA = 0.f, dwBA = 0.f;
    float gtA0 = 1.f, gtA1 = 1.f, gfrA = 0.f, scalA = 0.f;
    float zcB = 0.f, zhB_ = 0.f, fzB = 0.f, gzB = 1.f, dwAB = 0.f, dwBB = 0.f;
    float gtB0 = 1.f, gtB1 = 1.f, gfrB = 0.f, scalB = 0.f;

    // ---- init ybfZ from z0 (rows >= RPB zeroed); stage ax for t=0
    for (int i = tid; i < 1024; i += 512) {
        int r = i >> 6;
        float v = (i < RPB * L) ? z0buf[(size_t)r_base * L + i] : 0.f;
        ybfZ[i ^ ((r & 7) << 3)] = f2bf(v);
    }
    axS[tid] = axbuf[((size_t)0 * RTOT + r_base) * L + tid];
    if (ownB) axS[512 + tid] = axbuf[((size_t)0 * RTOT + r_base) * L + 512 + tid];
    __syncthreads();

    auto gprepA = [&](float v) {
        float x = (v - GYMIN) * GINVDY;
        x = fminf(fmaxf(x, 0.0f), (float)(GNT - 2) + 0.999f);
        int ii = (int)x;
        gfrA = x - (float)ii;
        const float* tl = gtab + ((size_t)olA << 12);
        gtA0 = tl[ii];
        gtA1 = tl[ii + 1];
    };
    auto gprepB = [&](float v) {
        float x = (v - GYMIN) * GINVDY;
        x = fminf(fmaxf(x, 0.0f), (float)(GNT - 2) + 0.999f);
        int ii = (int)x;
        gfrB = x - (float)ii;
        const float* tl = gtab + ((size_t)olA << 12);   // olB == olA
        gtB0 = tl[ii];
        gtB1 = tl[ii + 1];
    };

    for (int t = 0; t < T; ++t) {
        // ---- PZ: z_enc (waves 0-3): MFMA + ax (from axS) -> zcS + ybfA
        if (wv < 4) {
            bf16x8 Z0 = *(const bf16x8*)&ybfZ[((rA << 6) + (kg << 3)) ^ sw];
            bf16x8 Z1 = *(const bf16x8*)&ybfZ[((rA << 6) + 32 + (kg << 3)) ^ sw];
            f32x4 acc = (f32x4){0.f, 0.f, 0.f, 0.f};
            acc = MFMA16(Z0, W0r0, acc);
            acc = MFMA16(Z1, W0r1, acc);
            #pragma unroll
            for (int rr = 0; rr < 4; ++rr) {
                int r = (kg << 2) + rr;
                float axv = (r < RPB) ? axS[(r << 6) + lZ] : 0.f;
                float v = acc[rr] + axv;
                zcS[r][lZ] = v;
                ybfA[((r << 6) + lZ) ^ ((r & 7) << 3)] = f2bf(v);
            }
        }
        bar_lgkm();

        #pragma clang loop unroll(disable)
        for (int d = 0; d < 3; ++d) {
            // ---- Pa: y[16][64] @ W1 (LDS) -> o1 ; owner prefetch + ax restage at d==0
            if (d == 0) {
                zcA = zcS[orowA][olA];
                zhA_ = zcA;
                gprepA(zcA);
                dwAA = dW[((size_t)(2 * t) * RTOT + r_base) * L + tid] * SQDT;
                dwBA = dW[((size_t)(2 * t + 1) * RTOT + r_base) * L + tid] * SQDT;
                int tn = (t + 1 < T) ? t + 1 : t;
                axS[tid] = axbuf[((size_t)tn * RTOT + r_base) * L + tid];
                if (ownB) {
                    zcB = zcS[orowB][olA];
                    zhB_ = zcB;
                    gprepB(zcB);
                    dwAB = dW[((size_t)(2 * t) * RTOT + r_base) * L + 512 + tid] * SQDT;
                    dwBB = dW[((size_t)(2 * t + 1) * RTOT + r_base) * L + 512 + tid] * SQDT;
                    axS[512 + tid] = axbuf[((size_t)tn * RTOT + r_base) * L + 512 + tid];
                }
            }
            {
                bf16x8 A0 = *(const bf16x8*)&ybfA[((rA << 6) + (kg << 3)) ^ sw];
                bf16x8 A1 = *(const bf16x8*)&ybfA[((rA << 6) + 32 + (kg << 3)) ^ sw];
                f32x4 acc[4];
                #pragma unroll
                for (int i2 = 0; i2 < 4; ++i2) {
                    acc[i2] = (f32x4){biasA[i2], biasA[i2], biasA[i2], biasA[i2]};
                    acc[i2] = MFMA16(A0, w1L[net * 2048 + ((na + i2) * 2 + 0) * 64 + lane], acc[i2]);
                    acc[i2] = MFMA16(A1, w1L[net * 2048 + ((na + i2) * 2 + 1) * 64 + lane], acc[i2]);
                }
                unsigned short* o1n = o1[net];
                #pragma unroll
                for (int i2 = 0; i2 < 4; ++i2) {
                    int c = ((na + i2) << 4) + rA;
                    #pragma unroll
                    for (int rr = 0; rr < 4; ++rr) {
                        int r = (kg << 2) + rr;
                        o1n[((r << 8) + c) ^ ((r & 7) << 3)] = f2bf(sigf(acc[i2][rr]));
                    }
                }
            }
            bar_lgkm();
            // ---- Pb: h1[16][256] @ W2 (regs) -> o2
            {
                const unsigned short* o1n = o1[net];
                f32x4 acc[4];
                #pragma unroll
                for (int i2 = 0; i2 < 4; ++i2)
                    acc[i2] = (f32x4){biasB[i2], biasB[i2], biasB[i2], biasB[i2]};
                #pragma unroll
                for (int kc = 0; kc < 8; ++kc) {
                    bf16x8 Ak = *(const bf16x8*)&o1n[((rA << 8) + (kc << 5) + (kg << 3)) ^ sw];
                    #pragma unroll
                    for (int i2 = 0; i2 < 4; ++i2)
                        acc[i2] = MFMA16(Ak, W2r[i2 * 8 + kc], acc[i2]);
                }
                unsigned short* o2n = o2[net];
                #pragma unroll
                for (int i2 = 0; i2 < 4; ++i2) {
                    int c = ((na + i2) << 4) + rA;
                    #pragma unroll
                    for (int rr = 0; rr < 4; ++rr) {
                        int r = (kg << 2) + rr;
                        o2n[((r << 8) + c) ^ ((r & 7) << 3)] = f2bf(sigf(acc[i2][rr]));
                    }
                }
            }
            bar_lgkm();
            // ---- Pc: h2[16][256] @ W3 (regs), full K per wave -> fh2
            {
                const unsigned short* o2n = o2[net];
                f32x4 acc = (f32x4){biasC, biasC, biasC, biasC};
                f32x4 accb = (f32x4){0.f, 0.f, 0.f, 0.f};
                #pragma unroll
                for (int kc = 0; kc < 4; ++kc) {
                    bf16x8 Ak0 = *(const bf16x8*)&o2n[((rA << 8) + ((2 * kc) << 5) + (kg << 3)) ^ sw];
                    bf16x8 Ak1 = *(const bf16x8*)&o2n[((rA << 8) + ((2 * kc + 1) << 5) + (kg << 3)) ^ sw];
                    acc  = MFMA16(Ak0, W3r[2 * kc], acc);
                    accb = MFMA16(Ak1, W3r[2 * kc + 1], accb);
                }
                int c = (n0c << 4) + rA;
                #pragma unroll
                for (int rr = 0; rr < 4; ++rr)
                    fh2[net][(kg << 2) + rr][c] = acc[rr] + accb[rr];
            }
            bar_lgkm();
            // ---- Pf: finalize + Heun update in owner registers
            {
                float fvA = fh2[0][orowA][olA];
                float hvA = fh2[1][orowA][olA];
                float gvA = gtA0 * (1.0f - gfrA) + gtA1 * gfrA;
                float uA = (fvA - hvA) / gvA;
                float usA = uA * uA;
                float fvB = 0.f, hvB = 0.f, gvB = 1.f, usB = 0.f;
                if (ownB) {
                    fvB = fh2[0][orowB][olA];
                    hvB = fh2[1][orowB][olA];
                    gvB = gtB0 * (1.0f - gfrB) + gtB1 * gfrB;
                    float uB = (fvB - hvB) / gvB;
                    usB = uB * uB;
                }
                if (d == 0) {
                    scalA += usA; fzA = fvA; gzA = gvA;
                    float y1 = zcA + fvA * DT + gvA * dwAA;
                    zhA_ = y1;
                    ybfA[tid ^ ((orowA & 7) << 3)] = f2bf(y1);
                    gprepA(y1);
                    if (ownB) {
                        scalB += usB; fzB = fvB; gzB = gvB;
                        float y1b = zcB + fvB * DT + gvB * dwAB;
                        zhB_ = y1b;
                        ybfA[(512 + tid) ^ ((orowB & 7) << 3)] = f2bf(y1b);
                        gprepB(y1b);
                    }
                } else if (d == 1) {
                    zcA += 0.5f * (fzA + fvA) * DT + 0.5f * (gzA + gvA) * dwAA;
                    scalA += 2.0f * usA;
                    float y2 = 2.f * zcA - zhA_ + fvA * DT + gvA * dwBA;
                    fzA = fvA; gzA = gvA;
                    ybfA[tid ^ ((orowA & 7) << 3)] = f2bf(y2);
                    gprepA(y2);
                    if (ownB) {
                        zcB += 0.5f * (fzB + fvB) * DT + 0.5f * (gzB + gvB) * dwAB;
                        scalB += 2.0f * usB;
                        float y2b = 2.f * zcB - zhB_ + fvB * DT + gvB * dwBB;
                        fzB = fvB; gzB = gvB;
                        ybfA[(512 + tid) ^ ((orowB & 7) << 3)] = f2bf(y2b);
                        gprepB(y2b);
                    }
                } else {
                    zcA += 0.5f * (fzA + fvA) * DT + 0.5f * (gzA + gvA) * dwBA;
                    scalA += usA;
                    z_all[((size_t)t * RTOT + r_base) * L + tid] = zcA;
                    ybfZ[tid ^ ((orowA & 7) << 3)] = f2bf(zcA);
                    if (ownB) {
                        zcB += 0.5f * (fzB + fvB) * DT + 0.5f * (gzB + gvB) * dwBB;
                        scalB += usB;
                        z_all[((size_t)t * RTOT + r_base) * L + 512 + tid] = zcB;
                        ybfZ[(512 + tid) ^ ((orowB & 7) << 3)] = f2bf(zcB);
                    }
                }
            }
            bar_lgkm();
        }
    }
    // ---- final KL reduction: rowlr[r] = 0.25*DT * sum_l scal(r,l)
    {
        float s = scalA;
        #pragma unroll
        for (int off = 32; off; off >>= 1) s += __shfl_xor(s, off);
        if (olA == 0) rowlr[r_base + orowA] = 0.25f * DT * s;
        float sb = ownB ? scalB : 0.f;
        #pragma unroll
        for (int off = 32; off; off >>= 1) sb += __shfl_xor(sb, off);
        if (ownB && olA == 0) rowlr[r_base + orowB] = 0.25f * DT * sb;
    }
}

// ---------------------------------------------------------------- projection
__global__ __launch_bounds__(256) void proj_kernel(const float* __restrict__ z_all,
                            const float* __restrict__ pw1, const float* __restrict__ pb1,
                            const float* __restrict__ pw2, const float* __restrict__ pb2,
                            const float* __restrict__ pw3, const float* __restrict__ pb3,
                            float* __restrict__ out) {
    int bid = blockIdx.x;            // (t*E + e)*NBG + bg
    int bg = bid % NBG; int te = bid / NBG; int e = te % E; int t = te / E;
    int tid = threadIdx.x;           // 256
    __shared__ float zs[BGRP][L];
    __shared__ float p1s[BGRP][H];
    __shared__ float p2s[BGRP][H];
    __shared__ float part3[D][BGRP];
    size_t rbase = (size_t)t * RTOT + e * B + bg * BGRP;
    for (int i = tid; i < BGRP * L; i += 256) {
        int j = i >> 6, ll = i & 63;
        zs[j][ll] = z_all[(rbase + j) * L + ll];
    }
    __syncthreads();
    {
        float bias = pb1[e * H + tid];
        float acc[BGRP];
        #pragma unroll
        for (int j = 0; j < BGRP; ++j) acc[j] = bias;
        const float* w = pw1 + (size_t)e * L * H + tid;
        #pragma unroll 4
        for (int k = 0; k < L; ++k) {
            float wv = w[(size_t)k * H];
            #pragma unroll
            for (int j = 0; j < BGRP; ++j) acc[j] += zs[j][k] * wv;
        }
        #pragma unroll
        for (int j = 0; j < BGRP; ++j) p1s[j][tid] = sigf(acc[j]);
    }
    __syncthreads();
    {
        float bias = pb2[e * H + tid];
        float acc[BGRP];
        #pragma unroll
        for (int j = 0; j < BGRP; ++j) acc[j] = bias;
        const float* w = pw2 + (size_t)e * H * H + tid;
        #pragma unroll 4
        for (int k = 0; k < H; ++k) {
            float wv = w[(size_t)k * H];
            #pragma unroll
            for (int j = 0; j < BGRP; ++j) acc[j] += p1s[j][k] * wv;
        }
        #pragma unroll
        for (int j = 0; j < BGRP; ++j) p2s[j][tid] = sigf(acc[j]);
    }
    __syncthreads();
    float acc3[BGRP];
    {
        int dd = tid & 127, kh = tid >> 7;
        #pragma unroll
        for (int j = 0; j < BGRP; ++j) acc3[j] = 0.f;
        const float* w = pw3 + (size_t)e * H * D + dd;
        #pragma unroll 4
        for (int k = kh * 128; k < kh * 128 + 128; ++k) {
            float wv = w[(size_t)k * D];
            #pragma unroll
            for (int j = 0; j < BGRP; ++j) acc3[j] += p2s[j][k] * wv;
        }
        if (kh == 1) {
            #pragma unroll
            for (int j = 0; j < BGRP; ++j) part3[dd][j] = acc3[j];
        }
    }
    __syncthreads();
    if (tid < D) {
        float bias = pb3[e * D + tid];
        #pragma unroll
        for (int j = 0; j < BGRP; ++j) {
            out[8 + ((size_t)e * S + (size_t)t * B + bg * BGRP + j) * D + tid]
                = acc3[j] + part3[tid][j] + bias;
        }
    }
}

// ---------------------------------------------------------------- final combine
__global__ void fin_kernel(const float* __restrict__ logqp0p, const float* __restrict__ rowlr,
                           float* __restrict__ out) {
    int e = threadIdx.x;
    if (e < E) {
        float acc = 0.f;
        for (int t = 0; t < T; ++t)
            for (int bg = 0; bg < NBG; ++bg)
                acc += logqp0p[(t * E + e) * NBG + bg];
        float s = 0.f;
        for (int b = 0; b < B; ++b) s += rowlr[e * B + b];
        out[e] = acc + s / (float)B;
    }
}

extern "C" void kernel_launch(void* const* d_in, const int* in_sizes, int n_in,
                              void* d_out, int out_size, void* d_ws, size_t ws_size,
                              hipStream_t stream) {
    const float* xs      = (const float*)d_in[0];
    const float* actions = (const float*)d_in[1];
    const float* z0n     = (const float*)d_in[2];
    const float* dWp     = (const float*)d_in[3];
    const float* ew1     = (const float*)d_in[4];
    const float* eb1     = (const float*)d_in[5];
    const float* ew2     = (const float*)d_in[6];
    const float* eb2     = (const float*)d_in[7];
    const float* qw      = (const float*)d_in[8];
    const float* qb      = (const float*)d_in[9];
    const float* aw      = (const float*)d_in[10];
    const float* ab      = (const float*)d_in[11];
    const float* fw1     = (const float*)d_in[12];
    const float* fb1     = (const float*)d_in[13];
    const float* fw2     = (const float*)d_in[14];
    const float* fb2     = (const float*)d_in[15];
    const float* fw3     = (const float*)d_in[16];
    const float* fb3     = (const float*)d_in[17];
    const float* hw1     = (const float*)d_in[18];
    const float* hb1     = (const float*)d_in[19];
    const float* hw2     = (const float*)d_in[20];
    const float* hb2     = (const float*)d_in[21];
    const float* hw3     = (const float*)d_in[22];
    const float* hb3     = (const float*)d_in[23];
    const float* gw1     = (const float*)d_in[24];
    const float* gb1     = (const float*)d_in[25];
    const float* gw2     = (const float*)d_in[26];
    const float* gb2     = (const float*)d_in[27];
    const float* pw1     = (const float*)d_in[28];
    const float* pb1     = (const float*)d_in[29];
    const float* pw2     = (const float*)d_in[30];
    const float* pb2     = (const float*)d_in[31];
    const float* pw3     = (const float*)d_in[32];
    const float* pb3     = (const float*)d_in[33];
    const float* pm      = (const float*)d_in[34];
    const float* pl      = (const float*)d_in[35];

    float* ws      = (float*)d_ws;
    float* z0buf   = ws;                       // 25600
    float* axbuf   = z0buf + 25600;            // 3072000
    float* z_all   = axbuf + 3072000;          // 3072000
    float* logqp0p = z_all + 3072000;          // 4800
    float* rowlr   = logqp0p + 4800;           // 400
    float* gtab    = rowlr + 400;              // 262144
    unsigned short* pku = (unsigned short*)(gtab + 262144);
    unsigned short* pk1 = pku;                 // 2*16384
    unsigned short* pk2 = pk1 + 32768;         // 2*65536
    unsigned short* pk3 = pk2 + 131072;        // 2*16384
    unsigned short* pkAW = pk3 + 32768;        // E*4096
    float* out     = (float*)d_out;

    packB_kernel<<<64,  256, 0, stream>>>(fw1, pk1,          64, 256);
    packB_kernel<<<64,  256, 0, stream>>>(hw1, pk1 + 16384,  64, 256);
    packB_kernel<<<256, 256, 0, stream>>>(fw2, pk2,          256, 256);
    packB_kernel<<<256, 256, 0, stream>>>(hw2, pk2 + 65536,  256, 256);
    packB_kernel<<<64,  256, 0, stream>>>(fw3, pk3,          256, 64);
    packB_kernel<<<64,  256, 0, stream>>>(hw3, pk3 + 16384,  256, 64);
    packAW_kernel<<<128, 256, 0, stream>>>(aw, pkAW);
    gtab_kernel<<<1024, 256, 0, stream>>>(gw1, gb1, gw2, gb2, gtab);
    enc_kernel<<<T * E * NBG, 256, 0, stream>>>(xs, z0n, ew1, eb1, ew2, eb2, qw, qb, pm, pl, z0buf, logqp0p);
    ax_kernel<<<T * E * NBG, 64, 0, stream>>>(xs, actions, aw, ab, axbuf);
    seq_kernel<<<NBLK, 512, 0, stream>>>(pkAW, dWp, z0buf, axbuf,
                                         pk1, pk2, pk3,
                                         fb1, hb1, fb2, hb2, fb3, hb3,
                                         gtab, z_all, rowlr);
    proj_kernel<<<T * E * NBG, 256, 0, stream>>>(z_all, pw1, pb1, pw2, pb2, pw3, pb3, out);
    fin_kernel<<<1, 64, 0, stream>>>(logqp0p, rowlr, out);
}